// Round 12
// baseline (522.488 us; speedup 1.0000x reference)
//
#include <hip/hip_runtime.h>
#include <hip/hip_bf16.h>
#include <stdint.h>

typedef unsigned short u16;

#define M_TOT 4096
#define N_TOT 11008
#define K_TOT 4096

typedef __attribute__((ext_vector_type(4))) int i32x4;
typedef __attribute__((ext_vector_type(4))) float f32x4;
typedef __attribute__((ext_vector_type(8))) short bf16x8;

typedef const __attribute__((address_space(1))) void* gptr_t;
typedef __attribute__((address_space(3))) void* lptr_t;

// ---------------- pre-pass: quantize x per-row to i8 ----------------

__global__ __launch_bounds__(256) void quant_x(const float* __restrict__ X,
                                               uint32_t* __restrict__ Xq,
                                               float* __restrict__ scales) {
  int row = blockIdx.x;  // 4096 rows of K_TOT
  int t = threadIdx.x;   // 256 thr; 16 floats each, held in regs (no second read)
  const float4* xr = reinterpret_cast<const float4*>(X + (size_t)row * K_TOT) + t * 4;
  float4 v[4];
  float m = 0.f;
#pragma unroll
  for (int i = 0; i < 4; ++i) {
    v[i] = xr[i];
    m = fmaxf(m, fmaxf(fmaxf(fabsf(v[i].x), fabsf(v[i].y)),
                       fmaxf(fabsf(v[i].z), fabsf(v[i].w))));
  }
#pragma unroll
  for (int o = 1; o < 64; o <<= 1) m = fmaxf(m, __shfl_xor(m, o));
  __shared__ float wmax[4];
  int w = t >> 6, lane = t & 63;
  if (lane == 0) wmax[w] = m;
  __syncthreads();
  m = fmaxf(fmaxf(wmax[0], wmax[1]), fmaxf(wmax[2], wmax[3]));
  m = fmaxf(m, 1e-30f);
  float inv = 127.f / m;
  uint32_t q[4];
#pragma unroll
  for (int i = 0; i < 4; ++i) {
    int a = (int)rintf(v[i].x * inv), b = (int)rintf(v[i].y * inv);
    int c = (int)rintf(v[i].z * inv), d = (int)rintf(v[i].w * inv);
    q[i] = (a & 0xff) | ((b & 0xff) << 8) | ((c & 0xff) << 16) | ((uint32_t)(d & 0xff) << 24);
  }
  reinterpret_cast<uint4*>(Xq)[(size_t)row * 256 + t] = make_uint4(q[0], q[1], q[2], q[3]);
  if (t == 0) scales[row] = m / 127.f;
}

__device__ __forceinline__ uint32_t pk4(int4 v) {
  return (v.x & 0xff) | ((v.y & 0xff) << 8) | ((v.z & 0xff) << 16) |
         ((uint32_t)(v.w & 0xff) << 24);
}

// ========== 256x256 i8 GEMM with FUSED W int32->i8 dequant in B-staging ==========
// Round-5 geometry (198 us, 0 bank conflicts): 16x16x64 MFMA, chunk-XOR swizzle.
// A staged via global_load_lds from pre-quantized Xq; B staged via reg:
// 8x int4 W-loads -> pack 16 i8 -> 2x ds_write_b128 (same swizzled layout).
// Eliminates the 45-us cvt_w_q pre-pass; W (180 MB) is LLC-resident across blocks.
// 2 LDS buffers (64 KiB), one barrier per tile; vmcnt(0)+lgkmcnt(0) gate.

#define BM2 256
#define BN2 256
#define BKI 64
#define MT2 (M_TOT / BM2) /* 16 */
#define NT2 (N_TOT / BN2) /* 43 */
#define NWG2 (MT2 * NT2)  /* 688 */
#define NKTI (K_TOT / BKI) /* 64 */

__global__ __launch_bounds__(512, 2) void gemm_i8_fw(const int8_t* __restrict__ Xq,
                                                     const int* __restrict__ W,
                                                     const float* __restrict__ rowsc,
                                                     const float* __restrict__ scale,
                                                     const float* __restrict__ bias,
                                                     float* __restrict__ Out) {
  // 2 K-tile buffers: each = A[256][64]i8 ++ B[256][64]i8 = 32 KiB
  __shared__ __align__(16) uint8_t lds[2][32768];

  int bid = blockIdx.x;
  // bijective XCD swizzle (688 % 8 == 0); mt-inner -> same-XCD blocks share B-panel
  int swz = (bid & 7) * (NWG2 / 8) + (bid >> 3);
  int mt = swz & (MT2 - 1);
  int nt = swz >> 4;
  int row0 = mt * BM2, col0 = nt * BN2;

  int t = threadIdx.x;
  int lane = t & 63, w = t >> 6;     // 8 waves
  int wm = w >> 2, wn = w & 3;       // 2 x 4 wave grid
  int lr = lane & 15, lk = lane >> 4;

  // ---- staging addresses (round-5 verbatim; measured 0 bank conflicts) ----
  int ci = lane & 3;
  int rA = w * 16 + (lane >> 2);              // 0..127
  int cswz = ci ^ ((rA >> 1) & 3);            // involution, both sides
  size_t g0 = (size_t)(row0 + rA) * K_TOT + (size_t)(cswz * 16);
  size_t g1 = (size_t)(row0 + 128 + rA) * K_TOT + (size_t)(cswz * 16);
  // B element offsets — valid for W int32 indexing (Wq[i] came from W[i])
  size_t gB0 = (size_t)(col0 + rA) * K_TOT + (size_t)(cswz * 16);
  size_t gB1 = (size_t)(col0 + 128 + rA) * K_TOT + (size_t)(cswz * 16);

  auto stageA = [&](int kt) {
    size_t ko = (size_t)kt * BKI;
    char* lb = (char*)(&lds[kt & 1][0]) + w * 1024;
    __builtin_amdgcn_global_load_lds((gptr_t)(const void*)(Xq + g0 + ko), (lptr_t)(void*)(lb), 16, 0, 0);
    __builtin_amdgcn_global_load_lds((gptr_t)(const void*)(Xq + g1 + ko), (lptr_t)(void*)(lb + 8192), 16, 0, 0);
  };

  // ---- per-lane 16x16 fragment LDS byte offsets, swizzled, loop-invariant ----
  int aoff[8], boff[4];
#pragma unroll
  for (int m = 0; m < 8; ++m) {
    int ar = wm * 128 + m * 16 + lr;
    aoff[m] = ar * BKI + ((lk ^ ((ar >> 1) & 3)) << 4);
  }
#pragma unroll
  for (int n = 0; n < 4; ++n) {
    int br = wn * 64 + n * 16 + lr;
    boff[n] = 16384 + br * BKI + ((lk ^ ((br >> 1) & 3)) << 4);
  }

  i32x4 acc[8][4] = {};

  // ---- prologue: stage tile 0 (A via DMA, B via reg-pack) ----
  {
    const int4* p0 = reinterpret_cast<const int4*>(W + gB0);
    const int4* p1 = reinterpret_cast<const int4*>(W + gB1);
    int4 w0[4], w1[4];
#pragma unroll
    for (int j = 0; j < 4; ++j) { w0[j] = p0[j]; w1[j] = p1[j]; }
    stageA(0);
    uint4 q0 = make_uint4(pk4(w0[0]), pk4(w0[1]), pk4(w0[2]), pk4(w0[3]));
    uint4 q1 = make_uint4(pk4(w1[0]), pk4(w1[1]), pk4(w1[2]), pk4(w1[3]));
    char* nb = (char*)(&lds[0][0]) + w * 1024 + lane * 16;
    *reinterpret_cast<uint4*>(nb + 16384) = q0;
    *reinterpret_cast<uint4*>(nb + 24576) = q1;
    asm volatile("s_waitcnt vmcnt(0) lgkmcnt(0)" ::: "memory");
    __builtin_amdgcn_s_barrier();
    asm volatile("" ::: "memory");
  }

  // ---- main loop: one barrier per K-tile ----
  for (int kt = 0; kt < NKTI; ++kt) {
    const uint8_t* sb = &lds[kt & 1][0];
    i32x4 af[8], bfv[4];
#pragma unroll
    for (int m = 0; m < 8; ++m)
      af[m] = *reinterpret_cast<const i32x4*>(sb + aoff[m]);
#pragma unroll
    for (int n = 0; n < 4; ++n)
      bfv[n] = *reinterpret_cast<const i32x4*>(sb + boff[n]);

    int4 w0[4], w1[4];
    if (kt + 1 < NKTI) {
      size_t ko = (size_t)(kt + 1) * BKI;
      const int4* p0 = reinterpret_cast<const int4*>(W + gB0 + ko);
      const int4* p1 = reinterpret_cast<const int4*>(W + gB1 + ko);
#pragma unroll
      for (int j = 0; j < 4; ++j) { w0[j] = p0[j]; w1[j] = p1[j]; }
      stageA(kt + 1);   // DMA + B-loads run under MFMA
    }

    __builtin_amdgcn_s_setprio(1);
#pragma unroll
    for (int m = 0; m < 8; ++m)
#pragma unroll
      for (int n = 0; n < 4; ++n)
        acc[m][n] = __builtin_amdgcn_mfma_i32_16x16x64_i8(af[m], bfv[n], acc[m][n], 0, 0, 0);
    __builtin_amdgcn_s_setprio(0);

    if (kt + 1 < NKTI) {
      uint4 q0 = make_uint4(pk4(w0[0]), pk4(w0[1]), pk4(w0[2]), pk4(w0[3]));
      uint4 q1 = make_uint4(pk4(w1[0]), pk4(w1[1]), pk4(w1[2]), pk4(w1[3]));
      char* nb = (char*)(&lds[(kt + 1) & 1][0]) + w * 1024 + lane * 16;
      *reinterpret_cast<uint4*>(nb + 16384) = q0;
      *reinterpret_cast<uint4*>(nb + 24576) = q1;
      asm volatile("s_waitcnt vmcnt(0) lgkmcnt(0)" ::: "memory");  // A DMA + B writes done
      __builtin_amdgcn_s_barrier();
      asm volatile("" ::: "memory");
    }
  }

  // ---- epilogue: out = acc * (rowscale * scale) + bias ----
  float scl = scale[0];
  float bv[4];
#pragma unroll
  for (int n = 0; n < 4; ++n)
    bv[n] = bias[col0 + wn * 64 + n * 16 + lr];
#pragma unroll
  for (int m = 0; m < 8; ++m) {
    int rb = row0 + wm * 128 + m * 16 + lk * 4;   // 4-aligned
    f32x4 srv = *reinterpret_cast<const f32x4*>(rowsc + rb);
#pragma unroll
    for (int n = 0; n < 4; ++n) {
      int col = col0 + wn * 64 + n * 16 + lr;
#pragma unroll
      for (int r = 0; r < 4; ++r)
        Out[(size_t)(rb + r) * N_TOT + col] = (float)acc[m][n][r] * (srv[r] * scl) + bv[n];
    }
  }
}

// ---------------- fallback: fused dequant bf16 GEMM (no ws needed) ----------------

#define BM 128
#define BN 128
#define BK 32
#define MT (M_TOT / BM)
#define NT (N_TOT / BN)
#define NWG (MT * NT)
#define NK (K_TOT / BK)

__device__ __forceinline__ unsigned pk2_rne(float lo, float hi) {
  unsigned a = __builtin_bit_cast(unsigned, lo);
  unsigned b = __builtin_bit_cast(unsigned, hi);
  a += 0x7FFFu + ((a >> 16) & 1u);
  b += 0x7FFFu + ((b >> 16) & 1u);
  return (a >> 16) | (b & 0xFFFF0000u);
}

__device__ __forceinline__ void mfma_step(const u16* sa, const u16* sb,
                                          f32x4 acc[4][4], int arow, int brow, int lk) {
  bf16x8 af[4], bfv[4];
#pragma unroll
  for (int i = 0; i < 4; ++i)
    af[i] = *reinterpret_cast<const bf16x8*>(&sa[(arow + i * 16) * BK + lk * 8]);
#pragma unroll
  for (int i = 0; i < 4; ++i)
    bfv[i] = *reinterpret_cast<const bf16x8*>(&sb[(brow + i * 16) * BK + lk * 8]);
#pragma unroll
  for (int mi = 0; mi < 4; ++mi)
#pragma unroll
    for (int ni = 0; ni < 4; ++ni)
      acc[mi][ni] = __builtin_amdgcn_mfma_f32_16x16x32_bf16(af[mi], bfv[ni], acc[mi][ni], 0, 0, 0);
}

__global__ __launch_bounds__(256, 2) void gemm_fused(const float* __restrict__ X,
                                                     const int* __restrict__ W,
                                                     const float* __restrict__ scale,
                                                     const float* __restrict__ bias,
                                                     float* __restrict__ Out) {
  __shared__ __align__(16) u16 sA[2][BM * BK];
  __shared__ __align__(16) u16 sB[2][BN * BK];

  int bid = blockIdx.x;
  int swzf = (bid & 7) * (NWG / 8) + (bid >> 3);
  int mt = swzf & (MT - 1);
  int nt = swzf >> 5;
  int row0 = mt * BM, col0 = nt * BN;

  int t = threadIdx.x;
  int lane = t & 63, w = t >> 6;
  int wm = w >> 1, wn = w & 1;
  int lr = lane & 15, lk = lane >> 4;

  int srow = t >> 3;
  int scol = (t & 7) * 4;
  const float* xg = X + (size_t)row0 * K_TOT;
  const int* wg = W + (size_t)col0 * K_TOT;

  f32x4 acc[4][4] = {};
  float4 ar[4];
  int4 br[4];

  auto load_t = [&](int kt) {
    int k0 = kt * BK;
#pragma unroll
    for (int i = 0; i < 4; ++i) {
      int r = i * 32 + srow;
      ar[i] = *reinterpret_cast<const float4*>(&xg[(size_t)r * K_TOT + k0 + scol]);
      br[i] = *reinterpret_cast<const int4*>(&wg[(size_t)r * K_TOT + k0 + scol]);
    }
  };
  auto store_t = [&](int buf) {
#pragma unroll
    for (int i = 0; i < 4; ++i) {
      int r = i * 32 + srow;
      uint2 a2, b2;
      a2.x = pk2_rne(ar[i].x, ar[i].y);
      a2.y = pk2_rne(ar[i].z, ar[i].w);
      b2.x = pk2_rne((float)br[i].x, (float)br[i].y);
      b2.y = pk2_rne((float)br[i].z, (float)br[i].w);
      *reinterpret_cast<uint2*>(&sA[buf][r * BK + scol]) = a2;
      *reinterpret_cast<uint2*>(&sB[buf][r * BK + scol]) = b2;
    }
  };

  load_t(0);
  store_t(0);
  __syncthreads();
  int cur = 0;
  for (int kt = 0; kt < NK; ++kt) {
    if (kt + 1 < NK) load_t(kt + 1);
    mfma_step(&sA[cur][0], &sB[cur][0], acc, wm * 64 + lr, wn * 64 + lr, lk);
    if (kt + 1 < NK) store_t(cur ^ 1);
    __syncthreads();
    cur ^= 1;
  }

  float scl = scale[0];
#pragma unroll
  for (int mi = 0; mi < 4; ++mi) {
    int rb = row0 + wm * 64 + mi * 16 + lk * 4;
#pragma unroll
    for (int ni = 0; ni < 4; ++ni) {
      int col = col0 + wn * 64 + ni * 16 + lr;
      float bvv = bias[col];
#pragma unroll
      for (int r = 0; r < 4; ++r)
        Out[(size_t)(rb + r) * N_TOT + col] = acc[mi][ni][r] * scl + bvv;
    }
  }
}

// ---------------- launch ----------------

extern "C" void kernel_launch(void* const* d_in, const int* in_sizes, int n_in,
                              void* d_out, int out_size, void* d_ws, size_t ws_size,
                              hipStream_t stream) {
  const float* X = (const float*)d_in[0];
  const int* W = (const int*)d_in[1];
  const float* scale = (const float*)d_in[2];
  const float* bias = (const float*)d_in[3];
  float* Out = (float*)d_out;

  const size_t xq_bytes = (size_t)M_TOT * K_TOT;  // 16.8 MB
  const size_t need = xq_bytes + (size_t)M_TOT * sizeof(float);

  if (ws_size >= need) {
    int8_t* Xq = (int8_t*)d_ws;
    float* rowsc = (float*)(Xq + xq_bytes);
    quant_x<<<M_TOT, 256, 0, stream>>>(X, (uint32_t*)Xq, rowsc);
    gemm_i8_fw<<<NWG2, 512, 0, stream>>>(Xq, W, rowsc, scale, bias, Out);
  } else {
    gemm_fused<<<NWG, 256, 0, stream>>>(X, W, scale, bias, Out);
  }
}

// Round 13
// 249.777 us; speedup vs baseline: 2.0918x; 2.0918x over previous
//
#include <hip/hip_runtime.h>
#include <hip/hip_bf16.h>
#include <stdint.h>

typedef unsigned short u16;

#define M_TOT 4096
#define N_TOT 11008
#define K_TOT 4096

typedef __attribute__((ext_vector_type(4))) int i32x4;
typedef __attribute__((ext_vector_type(4))) float f32x4;
typedef __attribute__((ext_vector_type(8))) short bf16x8;

typedef const __attribute__((address_space(1))) void* gptr_t;
typedef __attribute__((address_space(3))) void* lptr_t;

// ---------------- pre-pass: quantize x per-row to i8, pack W to i8 ----------------

__global__ __launch_bounds__(256) void quant_x(const float* __restrict__ X,
                                               uint32_t* __restrict__ Xq,
                                               float* __restrict__ scales) {
  int row = blockIdx.x;  // 4096 rows of K_TOT
  int t = threadIdx.x;   // 256 thr; 16 floats each, held in regs (no second read)
  const float4* xr = reinterpret_cast<const float4*>(X + (size_t)row * K_TOT) + t * 4;
  float4 v[4];
  float m = 0.f;
#pragma unroll
  for (int i = 0; i < 4; ++i) {
    v[i] = xr[i];
    m = fmaxf(m, fmaxf(fmaxf(fabsf(v[i].x), fabsf(v[i].y)),
                       fmaxf(fabsf(v[i].z), fabsf(v[i].w))));
  }
#pragma unroll
  for (int o = 1; o < 64; o <<= 1) m = fmaxf(m, __shfl_xor(m, o));
  __shared__ float wmax[4];
  int w = t >> 6, lane = t & 63;
  if (lane == 0) wmax[w] = m;
  __syncthreads();
  m = fmaxf(fmaxf(wmax[0], wmax[1]), fmaxf(wmax[2], wmax[3]));
  m = fmaxf(m, 1e-30f);
  float inv = 127.f / m;
  uint32_t q[4];
#pragma unroll
  for (int i = 0; i < 4; ++i) {
    int a = (int)rintf(v[i].x * inv), b = (int)rintf(v[i].y * inv);
    int c = (int)rintf(v[i].z * inv), d = (int)rintf(v[i].w * inv);
    q[i] = (a & 0xff) | ((b & 0xff) << 8) | ((c & 0xff) << 16) | ((uint32_t)(d & 0xff) << 24);
  }
  reinterpret_cast<uint4*>(Xq)[(size_t)row * 256 + t] = make_uint4(q[0], q[1], q[2], q[3]);
  if (t == 0) scales[row] = m / 127.f;
}

__global__ __launch_bounds__(256) void cvt_w_q(const int* __restrict__ W,
                                               uint32_t* __restrict__ Wq, int n4) {
  int i = blockIdx.x * 256 + threadIdx.x;
  int stride = gridDim.x * 256;
  for (; i < n4; i += stride) {
    int4 v = reinterpret_cast<const int4*>(W)[i];
    Wq[i] = (v.x & 0xff) | ((v.y & 0xff) << 8) | ((v.z & 0xff) << 16) |
            ((uint32_t)(v.w & 0xff) << 24);
  }
}

// ================= 256x256 deep-pipelined i8 GEMM, 2-phase K-tiles =====
// BK=64 i8: 4 LDS buffers (128 KiB), stage-3-ahead, counted vmcnt(8),
// chunk-XOR swizzle (measured 0 bank conflicts), per-phase
// {ds_read | stage | barrier | MFMA | barrier}. Best measured: 198 us GEMM.

#define BM2 256
#define BN2 256
#define BKI 64
#define MT2 (M_TOT / BM2) /* 16 */
#define NT2 (N_TOT / BN2) /* 43 */
#define NWG2 (MT2 * NT2)  /* 688 */
#define NKTI (K_TOT / BKI) /* 64 */

__global__ __launch_bounds__(512, 2) void gemm_i8_256(const int8_t* __restrict__ Xq,
                                                      const int8_t* __restrict__ Wq,
                                                      const float* __restrict__ rowsc,
                                                      const float* __restrict__ scale,
                                                      const float* __restrict__ bias,
                                                      float* __restrict__ Out) {
  // 4 K-tile buffers: each = A[256][64]i8 ++ B[256][64]i8 = 32 KiB
  __shared__ __align__(16) uint8_t lds[4][32768];

  int bid = blockIdx.x;
  // bijective XCD swizzle (688 % 8 == 0); mt-inner -> same-XCD blocks share B-panel
  int swz = (bid & 7) * (NWG2 / 8) + (bid >> 3);
  int mt = swz & (MT2 - 1);
  int nt = swz >> 4;
  int row0 = mt * BM2, col0 = nt * BN2;

  int t = threadIdx.x;
  int lane = t & 63, w = t >> 6;     // 8 waves
  int wm = w >> 2, wn = w & 3;       // 2 x 4 wave grid
  int lr = lane & 15, lk = lane >> 4;

  // ---- staging (measured 0 bank conflicts) ----
  int ci = lane & 3;
  int rA = w * 16 + (lane >> 2);              // 0..127
  int cswz = ci ^ ((rA >> 1) & 3);            // involution, both sides
  size_t g0 = (size_t)(row0 + rA) * K_TOT + (size_t)(cswz * 16);
  size_t g1 = (size_t)(row0 + 128 + rA) * K_TOT + (size_t)(cswz * 16);
  size_t g2 = (size_t)(col0 + rA) * K_TOT + (size_t)(cswz * 16);
  size_t g3 = (size_t)(col0 + 128 + rA) * K_TOT + (size_t)(cswz * 16);

  auto stageA = [&](int kt) {
    size_t ko = (size_t)kt * BKI;
    char* lb = (char*)(&lds[kt & 3][0]) + w * 1024;
    __builtin_amdgcn_global_load_lds((gptr_t)(const void*)(Xq + g0 + ko), (lptr_t)(void*)(lb), 16, 0, 0);
    __builtin_amdgcn_global_load_lds((gptr_t)(const void*)(Xq + g1 + ko), (lptr_t)(void*)(lb + 8192), 16, 0, 0);
  };
  auto stageB = [&](int kt) {
    size_t ko = (size_t)kt * BKI;
    char* lb = (char*)(&lds[kt & 3][0]) + w * 1024;
    __builtin_amdgcn_global_load_lds((gptr_t)(const void*)(Wq + g2 + ko), (lptr_t)(void*)(lb + 16384), 16, 0, 0);
    __builtin_amdgcn_global_load_lds((gptr_t)(const void*)(Wq + g3 + ko), (lptr_t)(void*)(lb + 24576), 16, 0, 0);
  };

  // ---- per-lane 16x16 fragment LDS byte offsets, swizzled, loop-invariant ----
  // A and B use the IDENTICAL (lane,byte)->k geometry, so the GEMM result is
  // invariant to the instruction's internal k-permutation.
  int aoff[8], boff[4];
#pragma unroll
  for (int m = 0; m < 8; ++m) {
    int ar = wm * 128 + m * 16 + lr;
    aoff[m] = ar * BKI + ((lk ^ ((ar >> 1) & 3)) << 4);
  }
#pragma unroll
  for (int n = 0; n < 4; ++n) {
    int br = wn * 64 + n * 16 + lr;
    boff[n] = 16384 + br * BKI + ((lk ^ ((br >> 1) & 3)) << 4);
  }

  i32x4 acc[8][4] = {};

  // coarse compute for the 3-tile drain
  auto compute_tile = [&](int kt) {
    const uint8_t* sb = &lds[kt & 3][0];
    i32x4 af[8], bfv[4];
#pragma unroll
    for (int m = 0; m < 8; ++m)
      af[m] = *reinterpret_cast<const i32x4*>(sb + aoff[m]);
#pragma unroll
    for (int n = 0; n < 4; ++n)
      bfv[n] = *reinterpret_cast<const i32x4*>(sb + boff[n]);
    __builtin_amdgcn_s_setprio(1);
#pragma unroll
    for (int m = 0; m < 8; ++m)
#pragma unroll
      for (int n = 0; n < 4; ++n)
        acc[m][n] = __builtin_amdgcn_mfma_i32_16x16x64_i8(af[m], bfv[n], acc[m][n], 0, 0, 0);
    __builtin_amdgcn_s_setprio(0);
  };

  // ---- prologue: 3 K-tiles in flight ----
  stageA(0); stageB(0);
  stageA(1); stageB(1);
  stageA(2); stageB(2);
  asm volatile("s_waitcnt vmcnt(8)" ::: "memory");  // tile 0 landed
  __builtin_amdgcn_s_barrier();
  asm volatile("" ::: "memory");

  // ---- main loop: 2 phases per K-tile, counted vmcnt, never drained ----
#pragma unroll 4
  for (int kt = 0; kt < NKTI - 3; ++kt) {  // 0..60
    const uint8_t* sb = &lds[kt & 3][0];
    i32x4 af[4], af2[4], bfv[4];

    // ======== phase 0: m0-3 x n0-3 ========
#pragma unroll
    for (int m = 0; m < 4; ++m)
      af[m] = *reinterpret_cast<const i32x4*>(sb + aoff[m]);
#pragma unroll
    for (int n = 0; n < 4; ++n)
      bfv[n] = *reinterpret_cast<const i32x4*>(sb + boff[n]);
    stageA(kt + 3);
    __builtin_amdgcn_s_barrier();
    __builtin_amdgcn_s_setprio(1);
#pragma unroll
    for (int m = 0; m < 4; ++m)
#pragma unroll
      for (int n = 0; n < 4; ++n)
        acc[m][n] = __builtin_amdgcn_mfma_i32_16x16x64_i8(af[m], bfv[n], acc[m][n], 0, 0, 0);
    __builtin_amdgcn_s_setprio(0);
    __builtin_amdgcn_s_barrier();
    asm volatile("" ::: "memory");

    // ======== phase 1: m4-7 x n0-3 (B reused in-reg) ========
#pragma unroll
    for (int m = 0; m < 4; ++m)
      af2[m] = *reinterpret_cast<const i32x4*>(sb + aoff[m + 4]);
    stageB(kt + 3);
    asm volatile("s_waitcnt vmcnt(8)" ::: "memory");  // tile kt+1 fully landed
    __builtin_amdgcn_s_barrier();
    __builtin_amdgcn_s_setprio(1);
#pragma unroll
    for (int m = 0; m < 4; ++m)
#pragma unroll
      for (int n = 0; n < 4; ++n)
        acc[m + 4][n] = __builtin_amdgcn_mfma_i32_16x16x64_i8(af2[m], bfv[n], acc[m + 4][n], 0, 0, 0);
    __builtin_amdgcn_s_setprio(0);
    __builtin_amdgcn_s_barrier();
    asm volatile("" ::: "memory");
  }

  // ---- drain tail ----
  compute_tile(NKTI - 3);                             // 61
  asm volatile("s_waitcnt vmcnt(4)" ::: "memory");    // tile 62 landed
  __builtin_amdgcn_s_barrier();
  asm volatile("" ::: "memory");
  compute_tile(NKTI - 2);                             // 62
  asm volatile("s_waitcnt vmcnt(0)" ::: "memory");    // tile 63 landed
  __builtin_amdgcn_s_barrier();
  asm volatile("" ::: "memory");
  compute_tile(NKTI - 1);                             // 63

  // ---- epilogue: out = acc * (rowscale * scale) + bias ----
  float scl = scale[0];
  float bv[4];
#pragma unroll
  for (int n = 0; n < 4; ++n)
    bv[n] = bias[col0 + wn * 64 + n * 16 + lr];
#pragma unroll
  for (int m = 0; m < 8; ++m) {
    int rb = row0 + wm * 128 + m * 16 + lk * 4;   // 4-aligned
    f32x4 srv = *reinterpret_cast<const f32x4*>(rowsc + rb);
#pragma unroll
    for (int n = 0; n < 4; ++n) {
      int col = col0 + wn * 64 + n * 16 + lr;
#pragma unroll
      for (int r = 0; r < 4; ++r)
        Out[(size_t)(rb + r) * N_TOT + col] = (float)acc[m][n][r] * (srv[r] * scl) + bv[n];
    }
  }
}

// ---------------- fallback: fused dequant bf16 GEMM (no ws needed) ----------------

#define BM 128
#define BN 128
#define BK 32
#define MT (M_TOT / BM)
#define NT (N_TOT / BN)
#define NWG (MT * NT)
#define NK (K_TOT / BK)

__device__ __forceinline__ unsigned pk2_rne(float lo, float hi) {
  unsigned a = __builtin_bit_cast(unsigned, lo);
  unsigned b = __builtin_bit_cast(unsigned, hi);
  a += 0x7FFFu + ((a >> 16) & 1u);
  b += 0x7FFFu + ((b >> 16) & 1u);
  return (a >> 16) | (b & 0xFFFF0000u);
}

__device__ __forceinline__ void mfma_step(const u16* sa, const u16* sb,
                                          f32x4 acc[4][4], int arow, int brow, int lk) {
  bf16x8 af[4], bfv[4];
#pragma unroll
  for (int i = 0; i < 4; ++i)
    af[i] = *reinterpret_cast<const bf16x8*>(&sa[(arow + i * 16) * BK + lk * 8]);
#pragma unroll
  for (int i = 0; i < 4; ++i)
    bfv[i] = *reinterpret_cast<const bf16x8*>(&sb[(brow + i * 16) * BK + lk * 8]);
#pragma unroll
  for (int mi = 0; mi < 4; ++mi)
#pragma unroll
    for (int ni = 0; ni < 4; ++ni)
      acc[mi][ni] = __builtin_amdgcn_mfma_f32_16x16x32_bf16(af[mi], bfv[ni], acc[mi][ni], 0, 0, 0);
}

__global__ __launch_bounds__(256, 2) void gemm_fused(const float* __restrict__ X,
                                                     const int* __restrict__ W,
                                                     const float* __restrict__ scale,
                                                     const float* __restrict__ bias,
                                                     float* __restrict__ Out) {
  __shared__ __align__(16) u16 sA[2][BM * BK];
  __shared__ __align__(16) u16 sB[2][BN * BK];

  int bid = blockIdx.x;
  int swzf = (bid & 7) * (NWG / 8) + (bid >> 3);
  int mt = swzf & (MT - 1);
  int nt = swzf >> 5;
  int row0 = mt * BM, col0 = nt * BN;

  int t = threadIdx.x;
  int lane = t & 63, w = t >> 6;
  int wm = w >> 1, wn = w & 1;
  int lr = lane & 15, lk = lane >> 4;

  int srow = t >> 3;
  int scol = (t & 7) * 4;
  const float* xg = X + (size_t)row0 * K_TOT;
  const int* wg = W + (size_t)col0 * K_TOT;

  f32x4 acc[4][4] = {};
  float4 ar[4];
  int4 br[4];

  auto load_t = [&](int kt) {
    int k0 = kt * BK;
#pragma unroll
    for (int i = 0; i < 4; ++i) {
      int r = i * 32 + srow;
      ar[i] = *reinterpret_cast<const float4*>(&xg[(size_t)r * K_TOT + k0 + scol]);
      br[i] = *reinterpret_cast<const int4*>(&wg[(size_t)r * K_TOT + k0 + scol]);
    }
  };
  auto store_t = [&](int buf) {
#pragma unroll
    for (int i = 0; i < 4; ++i) {
      int r = i * 32 + srow;
      uint2 a2, b2;
      a2.x = pk2_rne(ar[i].x, ar[i].y);
      a2.y = pk2_rne(ar[i].z, ar[i].w);
      b2.x = pk2_rne((float)br[i].x, (float)br[i].y);
      b2.y = pk2_rne((float)br[i].z, (float)br[i].w);
      *reinterpret_cast<uint2*>(&sA[buf][r * BK + scol]) = a2;
      *reinterpret_cast<uint2*>(&sB[buf][r * BK + scol]) = b2;
    }
  };

  load_t(0);
  store_t(0);
  __syncthreads();
  int cur = 0;
  for (int kt = 0; kt < NK; ++kt) {
    if (kt + 1 < NK) load_t(kt + 1);
    mfma_step(&sA[cur][0], &sB[cur][0], acc, wm * 64 + lr, wn * 64 + lr, lk);
    if (kt + 1 < NK) store_t(cur ^ 1);
    __syncthreads();
    cur ^= 1;
  }

  float scl = scale[0];
#pragma unroll
  for (int mi = 0; mi < 4; ++mi) {
    int rb = row0 + wm * 64 + mi * 16 + lk * 4;
#pragma unroll
    for (int ni = 0; ni < 4; ++ni) {
      int col = col0 + wn * 64 + ni * 16 + lr;
      float bvv = bias[col];
#pragma unroll
      for (int r = 0; r < 4; ++r)
        Out[(size_t)(rb + r) * N_TOT + col] = acc[mi][ni][r] * scl + bvv;
    }
  }
}

// ---------------- launch ----------------

extern "C" void kernel_launch(void* const* d_in, const int* in_sizes, int n_in,
                              void* d_out, int out_size, void* d_ws, size_t ws_size,
                              hipStream_t stream) {
  const float* X = (const float*)d_in[0];
  const int* W = (const int*)d_in[1];
  const float* scale = (const float*)d_in[2];
  const float* bias = (const float*)d_in[3];
  float* Out = (float*)d_out;

  const size_t xq_bytes = (size_t)M_TOT * K_TOT;  // 16.8 MB
  const size_t wq_bytes = (size_t)N_TOT * K_TOT;  // 45.1 MB
  const size_t need = xq_bytes + wq_bytes + (size_t)M_TOT * sizeof(float);

  if (ws_size >= need) {
    int8_t* Xq = (int8_t*)d_ws;
    int8_t* Wq = Xq + xq_bytes;
    float* rowsc = (float*)(Wq + wq_bytes);
    quant_x<<<M_TOT, 256, 0, stream>>>(X, (uint32_t*)Xq, rowsc);
    cvt_w_q<<<2048, 256, 0, stream>>>(W, (uint32_t*)Wq, (int)(wq_bytes / 4));
    gemm_i8_256<<<NWG2, 512, 0, stream>>>(Xq, Wq, rowsc, scale, bias, Out);
  } else {
    gemm_fused<<<NWG, 256, 0, stream>>>(X, W, scale, bias, Out);
  }
}